// Round 1
// baseline (400.987 us; speedup 1.0000x reference)
//
#include <hip/hip_runtime.h>
#include <hip/hip_bf16.h>

#define S_LEN 2048
#define HID_DIM 1024
#define NH 16
#define HD 64
#define MTOT 4096  // B*S

typedef __attribute__((ext_vector_type(8))) short short8;
typedef __attribute__((ext_vector_type(4))) float f32x4;

__device__ __forceinline__ float bf2f(unsigned short u) {
  union { unsigned int i; float f; } x; x.i = ((unsigned int)u) << 16; return x.f;
}
__device__ __forceinline__ unsigned short f2bf(float f) {
  union { float ff; unsigned int i; } x; x.ff = f;
  return (unsigned short)((x.i + 0x7fffu + ((x.i >> 16) & 1u)) >> 16);
}
__device__ __forceinline__ f32x4 mfma16(short8 a, short8 b, f32x4 c) {
  return __builtin_amdgcn_mfma_f32_16x16x32_bf16(a, b, c, 0, 0, 0);
}
__device__ __forceinline__ void gl_lds16(const unsigned short* g, unsigned short* l) {
  __builtin_amdgcn_global_load_lds(
      (const __attribute__((address_space(1))) unsigned int*)g,
      (__attribute__((address_space(3))) unsigned int*)l, 16, 0, 0);
}

// ---------------- f32 -> bf16 convert ----------------
__global__ __launch_bounds__(256) void cvt_f32_bf16(const float* __restrict__ src,
                                                    unsigned short* __restrict__ dst, int n4) {
  int i = blockIdx.x * 256 + threadIdx.x;
  if (i >= n4) return;
  float4 v = reinterpret_cast<const float4*>(src)[i];
  union { unsigned short u[4]; unsigned long long ll; } o;
  o.u[0] = f2bf(v.x); o.u[1] = f2bf(v.y); o.u[2] = f2bf(v.z); o.u[3] = f2bf(v.w);
  reinterpret_cast<unsigned long long*>(dst)[i] = o.ll;
}

// ---------------- GEMM core: C[128x128] += A[128xK] * W[128xK]^T (bf16, B^T layout) ----------------
__device__ __forceinline__ void gemm_core(const unsigned short* __restrict__ A,
                                          const unsigned short* __restrict__ W,
                                          unsigned short* As, unsigned short* Bs,
                                          int m0, int n0, f32x4 (&acc)[4][4]) {
  const int tid = threadIdx.x;
  const int lane = tid & 63;
  const int wrow = (tid >> 6) >> 1, wcol = (tid >> 6) & 1;
  const int lr = lane & 15, g = lane >> 4;
  const int r = tid >> 2, c8 = (tid & 3) * 8;  // staging: row r, 16B chunk c8 (ushorts)
  const unsigned short* ag0 = A + (size_t)(m0 + r) * HID_DIM + c8;
  const unsigned short* ag1 = ag0 + (size_t)64 * HID_DIM;
  const unsigned short* bg0 = W + (size_t)(n0 + r) * HID_DIM + c8;
  const unsigned short* bg1 = bg0 + (size_t)64 * HID_DIM;
  unsigned short* al0 = As + r * 32 + c8;   // byte offset == tid*16 : wave-linear
  unsigned short* al1 = al0 + 64 * 32;
  unsigned short* bl0 = Bs + r * 32 + c8;
  unsigned short* bl1 = bl0 + 64 * 32;
  for (int k0 = 0; k0 < HID_DIM; k0 += 32) {
    __syncthreads();
    gl_lds16(ag0 + k0, al0);
    gl_lds16(ag1 + k0, al1);
    gl_lds16(bg0 + k0, bl0);
    gl_lds16(bg1 + k0, bl1);
    __syncthreads();
    short8 af[4], bfr[4];
#pragma unroll
    for (int m = 0; m < 4; ++m)
      af[m] = *reinterpret_cast<const short8*>(&As[(wrow * 64 + m * 16 + lr) * 32 + g * 8]);
#pragma unroll
    for (int n = 0; n < 4; ++n)
      bfr[n] = *reinterpret_cast<const short8*>(&Bs[(wcol * 64 + n * 16 + lr) * 32 + g * 8]);
#pragma unroll
    for (int m = 0; m < 4; ++m)
#pragma unroll
      for (int n = 0; n < 4; ++n)
        acc[m][n] = mfma16(af[m], bfr[n], acc[m][n]);
  }
}

// ---------------- fused QKV projection GEMM ----------------
__global__ __launch_bounds__(256) void qkv_gemm(
    const unsigned short* __restrict__ Aq, const unsigned short* __restrict__ Ak,
    const unsigned short* __restrict__ Av,
    const unsigned short* __restrict__ Wq, const unsigned short* __restrict__ Wk,
    const unsigned short* __restrict__ Wv,
    const float* __restrict__ bq, const float* __restrict__ bk, const float* __restrict__ bv,
    unsigned short* __restrict__ Qp, unsigned short* __restrict__ Kp,
    unsigned short* __restrict__ Vt) {
  __shared__ __attribute__((aligned(16))) unsigned short As[128 * 32];
  __shared__ __attribute__((aligned(16))) unsigned short Bs[128 * 32];
  const int which = blockIdx.x >> 3;           // 0:Q 1:K 2:V
  const int n0 = (blockIdx.x & 7) * 128;
  const int m0 = blockIdx.y * 128;
  const unsigned short* A = which == 0 ? Aq : which == 1 ? Ak : Av;
  const unsigned short* W = which == 0 ? Wq : which == 1 ? Wk : Wv;
  const float* bias = which == 0 ? bq : which == 1 ? bk : bv;

  f32x4 acc[4][4];
  const f32x4 vzero = {0.f, 0.f, 0.f, 0.f};
#pragma unroll
  for (int m = 0; m < 4; ++m)
#pragma unroll
    for (int n = 0; n < 4; ++n) acc[m][n] = vzero;

  gemm_core(A, W, As, Bs, m0, n0, acc);

  const int lane = threadIdx.x & 63;
  const int wrow = (threadIdx.x >> 6) >> 1, wcol = (threadIdx.x >> 6) & 1;
  const int lr = lane & 15, g = lane >> 4;
#pragma unroll
  for (int m = 0; m < 4; ++m) {
    const int rbase = m0 + wrow * 64 + m * 16 + g * 4;
#pragma unroll
    for (int n = 0; n < 4; ++n) {
      const int col = n0 + wcol * 64 + n * 16 + lr;
      const float bcol = bias[col];
      if (which < 2) {
        unsigned short* O = which == 0 ? Qp : Kp;
#pragma unroll
        for (int rg = 0; rg < 4; ++rg)
          O[(size_t)(rbase + rg) * HID_DIM + col] = f2bf(acc[m][n][rg] + bcol);
      } else {
        // V: write transposed-per-head layout Vt[B][H][D][S]
        const int bb = rbase >> 11, s = rbase & 2047;
        const int h = col >> 6, d = col & 63;
        union { unsigned short u[4]; unsigned long long ll; } o;
#pragma unroll
        for (int rg = 0; rg < 4; ++rg) o.u[rg] = f2bf(acc[m][n][rg] + bcol);
        *reinterpret_cast<unsigned long long*>(
            &Vt[((size_t)(bb * NH + h) * HD + d) * S_LEN + s]) = o.ll;
      }
    }
  }
}

// ---------------- output GEMM: d_out = Xa * Wo^T + bo (f32 out) ----------------
__global__ __launch_bounds__(256) void out_gemm(const unsigned short* __restrict__ X,
                                                const unsigned short* __restrict__ Wo,
                                                const float* __restrict__ bo,
                                                float* __restrict__ out) {
  __shared__ __attribute__((aligned(16))) unsigned short As[128 * 32];
  __shared__ __attribute__((aligned(16))) unsigned short Bs[128 * 32];
  const int n0 = blockIdx.x * 128;
  const int m0 = blockIdx.y * 128;
  f32x4 acc[4][4];
  const f32x4 vzero = {0.f, 0.f, 0.f, 0.f};
#pragma unroll
  for (int m = 0; m < 4; ++m)
#pragma unroll
    for (int n = 0; n < 4; ++n) acc[m][n] = vzero;

  gemm_core(X, Wo, As, Bs, m0, n0, acc);

  const int lane = threadIdx.x & 63;
  const int wrow = (threadIdx.x >> 6) >> 1, wcol = (threadIdx.x >> 6) & 1;
  const int lr = lane & 15, g = lane >> 4;
#pragma unroll
  for (int m = 0; m < 4; ++m) {
    const int rbase = m0 + wrow * 64 + m * 16 + g * 4;
#pragma unroll
    for (int n = 0; n < 4; ++n) {
      const int col = n0 + wcol * 64 + n * 16 + lr;
      const float bcol = bo[col];
#pragma unroll
      for (int rg = 0; rg < 4; ++rg)
        out[(size_t)(rbase + rg) * HID_DIM + col] = acc[m][n][rg] + bcol;
    }
  }
}

// ---------------- flash attention with 5-bucket relative position ----------------
__global__ __launch_bounds__(256) void attn_kernel(
    const unsigned short* __restrict__ Qp, const unsigned short* __restrict__ Kp,
    const unsigned short* __restrict__ Vt, const float* __restrict__ relk,
    const float* __restrict__ relv, unsigned short* __restrict__ Xa) {
  __shared__ __attribute__((aligned(16))) unsigned short Qs[64][72];
  __shared__ __attribute__((aligned(16))) unsigned short Ps[4][16][72];
  __shared__ float projs[64][5];
  __shared__ float rvs[5][64];

  const int tid = threadIdx.x;
  const int lane = tid & 63;
  const int wid = tid >> 6;
  const int qbase = blockIdx.x * 64;
  const int bh = blockIdx.y;
  const int b = bh >> 4, h = bh & 15;
  const int lr = lane & 15, g = lane >> 4;
  const float QSCALE = 0.125f;  // 1/sqrt(HD)

  // stage scaled Q tile (bf16) into LDS
  for (int c = tid; c < 512; c += 256) {
    const int row = c >> 3, cc = (c & 7) * 8;
    short8 v = *reinterpret_cast<const short8*>(
        &Qp[(size_t)(b * S_LEN + qbase + row) * HID_DIM + h * HD + cc]);
    short8 o;
#pragma unroll
    for (int j = 0; j < 8; ++j) o[j] = (short)f2bf(bf2f((unsigned short)v[j]) * QSCALE);
    *reinterpret_cast<short8*>(&Qs[row][cc]) = o;
  }
  for (int i = tid; i < 320; i += 256) rvs[i >> 6][i & 63] = relv[i];
  __syncthreads();
  // proj[row][j] = (scaled q_row) . rel_k[j]
  for (int idx = tid; idx < 320; idx += 256) {
    const int j = idx >> 6, row = idx & 63;
    float acc = 0.f;
    for (int d = 0; d < 64; ++d) acc += bf2f(Qs[row][d]) * relk[j * 64 + d];
    projs[row][j] = acc;
  }
  __syncthreads();

  short8 aq0 = *reinterpret_cast<const short8*>(&Qs[wid * 16 + lr][g * 8]);
  short8 aq1 = *reinterpret_cast<const short8*>(&Qs[wid * 16 + lr][g * 8 + 32]);

  float pj[4][5];
#pragma unroll
  for (int r = 0; r < 4; ++r)
#pragma unroll
    for (int j = 0; j < 5; ++j) pj[r][j] = projs[wid * 16 + g * 4 + r][j];

  const f32x4 vzero = {0.f, 0.f, 0.f, 0.f};
  f32x4 accO[4];
#pragma unroll
  for (int n = 0; n < 4; ++n) accO[n] = vzero;
  float sp[4][5];
#pragma unroll
  for (int r = 0; r < 4; ++r)
#pragma unroll
    for (int j = 0; j < 5; ++j) sp[r][j] = 0.f;
  float mrun[4] = {-__builtin_inff(), -__builtin_inff(), -__builtin_inff(), -__builtin_inff()};

  const unsigned short* Kbase = Kp + (size_t)b * S_LEN * HID_DIM + h * HD;
  const unsigned short* Vbase = Vt + (size_t)bh * HD * S_LEN;

  for (int kb = 0; kb < S_LEN; kb += 64) {
    // S = Q K^T  (K fragments straight from global; rows are L1/L2 resident)
    f32x4 accS[4];
#pragma unroll
    for (int n = 0; n < 4; ++n) {
      const unsigned short* kp = Kbase + (size_t)(kb + n * 16 + lr) * HID_DIM + g * 8;
      short8 b0 = *reinterpret_cast<const short8*>(kp);
      short8 b1 = *reinterpret_cast<const short8*>(kp + 32);
      f32x4 z = mfma16(aq0, b0, vzero);
      accS[n] = mfma16(aq1, b1, z);
    }
    const bool mixed = (kb + 64 == qbase) || (kb == qbase) || (kb == qbase + 64);
    float newm[4];
#pragma unroll
    for (int r = 0; r < 4; ++r) newm[r] = mrun[r];
    if (!mixed) {
      const int jc = (kb < qbase) ? 0 : 4;
#pragma unroll
      for (int n = 0; n < 4; ++n)
#pragma unroll
        for (int r = 0; r < 4; ++r) {
          accS[n][r] += (jc == 0) ? pj[r][0] : pj[r][4];
          newm[r] = fmaxf(newm[r], accS[n][r]);
        }
    } else {
#pragma unroll
      for (int n = 0; n < 4; ++n) {
        const int kg = kb + n * 16 + lr;
#pragma unroll
        for (int r = 0; r < 4; ++r) {
          const int dist = kg - (qbase + wid * 16 + g * 4 + r);
          const int jj = dist < -2 ? 0 : (dist > 2 ? 4 : dist + 2);
          const float add = jj == 0 ? pj[r][0] : jj == 1 ? pj[r][1] : jj == 2 ? pj[r][2]
                           : jj == 3 ? pj[r][3] : pj[r][4];
          accS[n][r] += add;
          newm[r] = fmaxf(newm[r], accS[n][r]);
        }
      }
    }
    // row max across the 16-lane column group, then rescale running state
#pragma unroll
    for (int r = 0; r < 4; ++r) {
      float v = newm[r];
      v = fmaxf(v, __shfl_xor(v, 1));
      v = fmaxf(v, __shfl_xor(v, 2));
      v = fmaxf(v, __shfl_xor(v, 4));
      v = fmaxf(v, __shfl_xor(v, 8));
      const float fsc = __expf(mrun[r] - v);  // 0 on first tile (-inf)
      mrun[r] = v;
#pragma unroll
      for (int j = 0; j < 5; ++j) sp[r][j] *= fsc;
#pragma unroll
      for (int n = 0; n < 4; ++n) accO[n][r] *= fsc;
    }
    // P = exp(S - m); accumulate 5-bucket per-lane partials; stage P for transpose
#pragma unroll
    for (int n = 0; n < 4; ++n) {
      const int kg = kb + n * 16 + lr;
#pragma unroll
      for (int r = 0; r < 4; ++r) {
        const float p = __expf(accS[n][r] - mrun[r]);
        if (!mixed) {
          if (kb < qbase) sp[r][0] += p; else sp[r][4] += p;
        } else {
          const int dist = kg - (qbase + wid * 16 + g * 4 + r);
          const int jj = dist < -2 ? 0 : (dist > 2 ? 4 : dist + 2);
          sp[r][0] += (jj == 0) ? p : 0.f;
          sp[r][1] += (jj == 1) ? p : 0.f;
          sp[r][2] += (jj == 2) ? p : 0.f;
          sp[r][3] += (jj == 3) ? p : 0.f;
          sp[r][4] += (jj == 4) ? p : 0.f;
        }
        Ps[wid][g * 4 + r][n * 16 + lr] = f2bf(p);
      }
    }
    // O += P V  (P via per-wave LDS transpose; V rows contiguous thanks to Vt layout)
    short8 pa0 = *reinterpret_cast<const short8*>(&Ps[wid][lr][g * 8]);
    short8 pa1 = *reinterpret_cast<const short8*>(&Ps[wid][lr][g * 8 + 32]);
#pragma unroll
    for (int n = 0; n < 4; ++n) {
      const unsigned short* vp = Vbase + (size_t)(n * 16 + lr) * S_LEN + kb + g * 8;
      short8 b0 = *reinterpret_cast<const short8*>(vp);
      short8 b1 = *reinterpret_cast<const short8*>(vp + 32);
      accO[n] = mfma16(pa0, b0, accO[n]);
      accO[n] = mfma16(pa1, b1, accO[n]);
    }
  }

  // reduce bucket partials across the 16-lane group
#pragma unroll
  for (int r = 0; r < 4; ++r)
#pragma unroll
    for (int j = 0; j < 5; ++j) {
      float v = sp[r][j];
      v += __shfl_xor(v, 1);
      v += __shfl_xor(v, 2);
      v += __shfl_xor(v, 4);
      v += __shfl_xor(v, 8);
      sp[r][j] = v;
    }
  float rl[4];
#pragma unroll
  for (int r = 0; r < 4; ++r)
    rl[r] = 1.f / (sp[r][0] + sp[r][1] + sp[r][2] + sp[r][3] + sp[r][4]);
  // out = (O + sum_j s~_j * rel_v[j]) / l
#pragma unroll
  for (int n = 0; n < 4; ++n) {
    const int d = n * 16 + lr;
    const float rv0 = rvs[0][d], rv1 = rvs[1][d], rv2 = rvs[2][d], rv3 = rvs[3][d],
                rv4 = rvs[4][d];
#pragma unroll
    for (int r = 0; r < 4; ++r) {
      const float val = (accO[n][r] + sp[r][0] * rv0 + sp[r][1] * rv1 + sp[r][2] * rv2 +
                         sp[r][3] * rv3 + sp[r][4] * rv4) * rl[r];
      Xa[(size_t)(b * S_LEN + qbase + wid * 16 + g * 4 + r) * HID_DIM + h * HD + d] = f2bf(val);
    }
  }
}

extern "C" void kernel_launch(void* const* d_in, const int* in_sizes, int n_in,
                              void* d_out, int out_size, void* d_ws, size_t ws_size,
                              hipStream_t stream) {
  (void)in_sizes; (void)n_in; (void)out_size; (void)ws_size;
  const float* f_key   = (const float*)d_in[0];
  const float* f_query = (const float*)d_in[1];
  const float* f_value = (const float*)d_in[2];
  const float* Wq = (const float*)d_in[3];
  const float* bq = (const float*)d_in[4];
  const float* Wk = (const float*)d_in[5];
  const float* bk = (const float*)d_in[6];
  const float* Wv = (const float*)d_in[7];
  const float* bv = (const float*)d_in[8];
  const float* Wo = (const float*)d_in[9];
  const float* bo = (const float*)d_in[10];
  const float* relk = (const float*)d_in[11];
  const float* relv = (const float*)d_in[12];

  char* ws = (char*)d_ws;
  const size_t SZ = (size_t)MTOT * HID_DIM * sizeof(unsigned short);  // 8 MiB
  unsigned short* cq  = (unsigned short*)(ws + 0 * SZ);
  unsigned short* ck  = (unsigned short*)(ws + 1 * SZ);
  unsigned short* cv  = (unsigned short*)(ws + 2 * SZ);
  unsigned short* wqb = (unsigned short*)(ws + 3 * SZ);
  unsigned short* wkb = wqb + 1024 * 1024;
  unsigned short* wvb = wkb + 1024 * 1024;
  unsigned short* wob = wvb + 1024 * 1024;
  unsigned short* Qp  = (unsigned short*)(ws + 4 * SZ);
  unsigned short* Kp  = (unsigned short*)(ws + 5 * SZ);
  unsigned short* Vt  = (unsigned short*)(ws + 6 * SZ);
  unsigned short* xa  = cq;  // cq dead after qkv_gemm; reuse for attention output

  const int nIn4 = MTOT * HID_DIM / 4;
  const int nW4 = 1024 * 1024 / 4;
  cvt_f32_bf16<<<nIn4 / 256, 256, 0, stream>>>(f_query, cq, nIn4);
  cvt_f32_bf16<<<nIn4 / 256, 256, 0, stream>>>(f_key, ck, nIn4);
  cvt_f32_bf16<<<nIn4 / 256, 256, 0, stream>>>(f_value, cv, nIn4);
  cvt_f32_bf16<<<nW4 / 256, 256, 0, stream>>>(Wq, wqb, nW4);
  cvt_f32_bf16<<<nW4 / 256, 256, 0, stream>>>(Wk, wkb, nW4);
  cvt_f32_bf16<<<nW4 / 256, 256, 0, stream>>>(Wv, wvb, nW4);
  cvt_f32_bf16<<<nW4 / 256, 256, 0, stream>>>(Wo, wob, nW4);
  qkv_gemm<<<dim3(24, 32), dim3(256), 0, stream>>>(cq, ck, cv, wqb, wkb, wvb, bq, bk, bv,
                                                   Qp, Kp, Vt);
  attn_kernel<<<dim3(32, 32), dim3(256), 0, stream>>>(Qp, Kp, Vt, relk, relv, xa);
  out_gemm<<<dim3(8, 32), dim3(256), 0, stream>>>(xa, wob, bo, (float*)d_out);
}

// Round 5
// 343.793 us; speedup vs baseline: 1.1664x; 1.1664x over previous
//
#include <hip/hip_runtime.h>
#include <hip/hip_bf16.h>

#define S_LEN 2048
#define HID_DIM 1024
#define NH 16
#define HD 64
#define MTOT 4096  // B*S

typedef __attribute__((ext_vector_type(8))) short short8;
typedef __attribute__((ext_vector_type(4))) float f32x4;

__device__ __forceinline__ float bf2f(unsigned short u) {
  union { unsigned int i; float f; } x; x.i = ((unsigned int)u) << 16; return x.f;
}
__device__ __forceinline__ unsigned short f2bf(float f) {
  union { float ff; unsigned int i; } x; x.ff = f;
  return (unsigned short)((x.i + 0x7fffu + ((x.i >> 16) & 1u)) >> 16);
}
__device__ __forceinline__ f32x4 mfma16(short8 a, short8 b, f32x4 c) {
  return __builtin_amdgcn_mfma_f32_16x16x32_bf16(a, b, c, 0, 0, 0);
}
__device__ __forceinline__ void gl_lds16(const unsigned short* g, unsigned short* l) {
  __builtin_amdgcn_global_load_lds(
      (const __attribute__((address_space(1))) unsigned int*)g,
      (__attribute__((address_space(3))) unsigned int*)l, 16, 0, 0);
}

// ---------------- f32 -> bf16 converts (fused) ----------------
__global__ __launch_bounds__(256) void cvt3(const float* __restrict__ a, const float* __restrict__ b,
                                            const float* __restrict__ c, unsigned short* __restrict__ oa,
                                            unsigned short* __restrict__ ob, unsigned short* __restrict__ oc,
                                            int n4) {
  int i = blockIdx.x * 256 + threadIdx.x;
  if (i >= n4) return;
  const float* src = blockIdx.y == 0 ? a : blockIdx.y == 1 ? b : c;
  unsigned short* dst = blockIdx.y == 0 ? oa : blockIdx.y == 1 ? ob : oc;
  float4 v = reinterpret_cast<const float4*>(src)[i];
  union { unsigned short u[4]; unsigned long long ll; } o;
  o.u[0] = f2bf(v.x); o.u[1] = f2bf(v.y); o.u[2] = f2bf(v.z); o.u[3] = f2bf(v.w);
  reinterpret_cast<unsigned long long*>(dst)[i] = o.ll;
}
__global__ __launch_bounds__(256) void cvt4(const float* __restrict__ a, const float* __restrict__ b,
                                            const float* __restrict__ c, const float* __restrict__ d,
                                            unsigned short* __restrict__ oa, unsigned short* __restrict__ ob,
                                            unsigned short* __restrict__ oc, unsigned short* __restrict__ od,
                                            int n4) {
  int i = blockIdx.x * 256 + threadIdx.x;
  if (i >= n4) return;
  const float* src = blockIdx.y == 0 ? a : blockIdx.y == 1 ? b : blockIdx.y == 2 ? c : d;
  unsigned short* dst = blockIdx.y == 0 ? oa : blockIdx.y == 1 ? ob : blockIdx.y == 2 ? oc : od;
  float4 v = reinterpret_cast<const float4*>(src)[i];
  union { unsigned short u[4]; unsigned long long ll; } o;
  o.u[0] = f2bf(v.x); o.u[1] = f2bf(v.y); o.u[2] = f2bf(v.z); o.u[3] = f2bf(v.w);
  reinterpret_cast<unsigned long long*>(dst)[i] = o.ll;
}

// ---------------- GEMM core: C[128x128] += A[128xK] * W[128xK]^T (bf16, B^T layout) ----------------
__device__ __forceinline__ void gemm_core(const unsigned short* __restrict__ A,
                                          const unsigned short* __restrict__ W,
                                          unsigned short* As, unsigned short* Bs,
                                          int m0, int n0, f32x4 (&acc)[4][4]) {
  const int tid = threadIdx.x;
  const int lane = tid & 63;
  const int wrow = (tid >> 6) >> 1, wcol = (tid >> 6) & 1;
  const int lr = lane & 15, g = lane >> 4;
  const int r = tid >> 2, c8 = (tid & 3) * 8;
  const unsigned short* ag0 = A + (size_t)(m0 + r) * HID_DIM + c8;
  const unsigned short* ag1 = ag0 + (size_t)64 * HID_DIM;
  const unsigned short* bg0 = W + (size_t)(n0 + r) * HID_DIM + c8;
  const unsigned short* bg1 = bg0 + (size_t)64 * HID_DIM;
  unsigned short* al0 = As + r * 32 + c8;
  unsigned short* al1 = al0 + 64 * 32;
  unsigned short* bl0 = Bs + r * 32 + c8;
  unsigned short* bl1 = bl0 + 64 * 32;
  for (int k0 = 0; k0 < HID_DIM; k0 += 32) {
    __syncthreads();
    gl_lds16(ag0 + k0, al0);
    gl_lds16(ag1 + k0, al1);
    gl_lds16(bg0 + k0, bl0);
    gl_lds16(bg1 + k0, bl1);
    __syncthreads();
    short8 af[4], bfr[4];
#pragma unroll
    for (int m = 0; m < 4; ++m)
      af[m] = *reinterpret_cast<const short8*>(&As[(wrow * 64 + m * 16 + lr) * 32 + g * 8]);
#pragma unroll
    for (int n = 0; n < 4; ++n)
      bfr[n] = *reinterpret_cast<const short8*>(&Bs[(wcol * 64 + n * 16 + lr) * 32 + g * 8]);
#pragma unroll
    for (int m = 0; m < 4; ++m)
#pragma unroll
      for (int n = 0; n < 4; ++n)
        acc[m][n] = mfma16(af[m], bfr[n], acc[m][n]);
  }
}

// ---------------- fused QKV projection GEMM ----------------
__global__ __launch_bounds__(256) void qkv_gemm(
    const unsigned short* __restrict__ Aq, const unsigned short* __restrict__ Ak,
    const unsigned short* __restrict__ Av,
    const unsigned short* __restrict__ Wq, const unsigned short* __restrict__ Wk,
    const unsigned short* __restrict__ Wv,
    const float* __restrict__ bq, const float* __restrict__ bk, const float* __restrict__ bv,
    unsigned short* __restrict__ Qp, unsigned short* __restrict__ Kp,
    unsigned short* __restrict__ Vt) {
  __shared__ __attribute__((aligned(16))) unsigned short As[128 * 32];
  __shared__ __attribute__((aligned(16))) unsigned short Bs[128 * 32];
  const int which = blockIdx.x >> 3;
  const int n0 = (blockIdx.x & 7) * 128;
  const int m0 = blockIdx.y * 128;
  const unsigned short* A = which == 0 ? Aq : which == 1 ? Ak : Av;
  const unsigned short* W = which == 0 ? Wq : which == 1 ? Wk : Wv;
  const float* bias = which == 0 ? bq : which == 1 ? bk : bv;

  f32x4 acc[4][4];
  const f32x4 vzero = {0.f, 0.f, 0.f, 0.f};
#pragma unroll
  for (int m = 0; m < 4; ++m)
#pragma unroll
    for (int n = 0; n < 4; ++n) acc[m][n] = vzero;

  gemm_core(A, W, As, Bs, m0, n0, acc);

  const int lane = threadIdx.x & 63;
  const int wrow = (threadIdx.x >> 6) >> 1, wcol = (threadIdx.x >> 6) & 1;
  const int lr = lane & 15, g = lane >> 4;
#pragma unroll
  for (int m = 0; m < 4; ++m) {
    const int rbase = m0 + wrow * 64 + m * 16 + g * 4;
#pragma unroll
    for (int n = 0; n < 4; ++n) {
      const int col = n0 + wcol * 64 + n * 16 + lr;
      const float bcol = bias[col];
      if (which < 2) {
        unsigned short* O = which == 0 ? Qp : Kp;
#pragma unroll
        for (int rg = 0; rg < 4; ++rg)
          O[(size_t)(rbase + rg) * HID_DIM + col] = f2bf(acc[m][n][rg] + bcol);
      } else {
        const int bb = rbase >> 11, s = rbase & 2047;
        const int h = col >> 6, d = col & 63;
        union { unsigned short u[4]; unsigned long long ll; } o;
#pragma unroll
        for (int rg = 0; rg < 4; ++rg) o.u[rg] = f2bf(acc[m][n][rg] + bcol);
        *reinterpret_cast<unsigned long long*>(
            &Vt[((size_t)(bb * NH + h) * HD + d) * S_LEN + s]) = o.ll;
      }
    }
  }
}

// ---------------- output GEMM ----------------
__global__ __launch_bounds__(256) void out_gemm(const unsigned short* __restrict__ X,
                                                const unsigned short* __restrict__ Wo,
                                                const float* __restrict__ bo,
                                                float* __restrict__ out) {
  __shared__ __attribute__((aligned(16))) unsigned short As[128 * 32];
  __shared__ __attribute__((aligned(16))) unsigned short Bs[128 * 32];
  const int n0 = blockIdx.x * 128;
  const int m0 = blockIdx.y * 128;
  f32x4 acc[4][4];
  const f32x4 vzero = {0.f, 0.f, 0.f, 0.f};
#pragma unroll
  for (int m = 0; m < 4; ++m)
#pragma unroll
    for (int n = 0; n < 4; ++n) acc[m][n] = vzero;

  gemm_core(X, Wo, As, Bs, m0, n0, acc);

  const int lane = threadIdx.x & 63;
  const int wrow = (threadIdx.x >> 6) >> 1, wcol = (threadIdx.x >> 6) & 1;
  const int lr = lane & 15, g = lane >> 4;
#pragma unroll
  for (int m = 0; m < 4; ++m) {
    const int rbase = m0 + wrow * 64 + m * 16 + g * 4;
#pragma unroll
    for (int n = 0; n < 4; ++n) {
      const int col = n0 + wcol * 64 + n * 16 + lr;
      const float bcol = bo[col];
#pragma unroll
      for (int rg = 0; rg < 4; ++rg)
        out[(size_t)(rbase + rg) * HID_DIM + col] = acc[m][n][rg] + bcol;
    }
  }
}

// ---------------- flash attention (round-1 structure, verbatim; + load-ILP + fence) ----------------
__global__ __launch_bounds__(256) void attn_kernel(
    const unsigned short* __restrict__ Qp, const unsigned short* __restrict__ Kp,
    const unsigned short* __restrict__ Vt, const float* __restrict__ relk,
    const float* __restrict__ relv, unsigned short* __restrict__ Xa) {
  __shared__ __attribute__((aligned(16))) unsigned short Qs[64][72];
  __shared__ __attribute__((aligned(16))) unsigned short Ps[4][16][72];
  __shared__ float projs[64][5];
  __shared__ float rvs[5][64];

  const int tid = threadIdx.x;
  const int lane = tid & 63;
  const int wid = tid >> 6;
  const int qbase = blockIdx.x * 64;
  const int bh = blockIdx.y;
  const int b = bh >> 4, h = bh & 15;
  const int lr = lane & 15, g = lane >> 4;
  const float QSCALE = 0.125f;  // 1/sqrt(HD)

  // stage scaled Q tile (bf16) into LDS
  for (int c = tid; c < 512; c += 256) {
    const int row = c >> 3, cc = (c & 7) * 8;
    short8 v = *reinterpret_cast<const short8*>(
        &Qp[(size_t)(b * S_LEN + qbase + row) * HID_DIM + h * HD + cc]);
    short8 o;
#pragma unroll
    for (int j = 0; j < 8; ++j) o[j] = (short)f2bf(bf2f((unsigned short)v[j]) * QSCALE);
    *reinterpret_cast<short8*>(&Qs[row][cc]) = o;
  }
  for (int i = tid; i < 320; i += 256) rvs[i >> 6][i & 63] = relv[i];
  __syncthreads();
  // proj[row][j] = (scaled q_row) . rel_k[j]
  for (int idx = tid; idx < 320; idx += 256) {
    const int j = idx >> 6, row = idx & 63;
    float acc = 0.f;
    for (int d = 0; d < 64; ++d) acc += bf2f(Qs[row][d]) * relk[j * 64 + d];
    projs[row][j] = acc;
  }
  __syncthreads();

  short8 aq0 = *reinterpret_cast<const short8*>(&Qs[wid * 16 + lr][g * 8]);
  short8 aq1 = *reinterpret_cast<const short8*>(&Qs[wid * 16 + lr][g * 8 + 32]);

  float pj[4][5];
#pragma unroll
  for (int r = 0; r < 4; ++r)
#pragma unroll
    for (int j = 0; j < 5; ++j) pj[r][j] = projs[wid * 16 + g * 4 + r][j];

  const f32x4 vzero = {0.f, 0.f, 0.f, 0.f};
  f32x4 accO[4];
#pragma unroll
  for (int n = 0; n < 4; ++n) accO[n] = vzero;
  float sp[4][5];
#pragma unroll
  for (int r = 0; r < 4; ++r)
#pragma unroll
    for (int j = 0; j < 5; ++j) sp[r][j] = 0.f;
  float mrun[4] = {-__builtin_inff(), -__builtin_inff(), -__builtin_inff(), -__builtin_inff()};

  const unsigned short* Kbase = Kp + (size_t)b * S_LEN * HID_DIM + h * HD;
  const unsigned short* Vbase = Vt + (size_t)bh * HD * S_LEN;

  for (int kb = 0; kb < S_LEN; kb += 64) {
    // --- all K fragment loads issued before the MFMAs (ILP) ---
    short8 kf[4][2];
#pragma unroll
    for (int n = 0; n < 4; ++n) {
      const unsigned short* kp = Kbase + (size_t)(kb + n * 16 + lr) * HID_DIM + g * 8;
      kf[n][0] = *reinterpret_cast<const short8*>(kp);
      kf[n][1] = *reinterpret_cast<const short8*>(kp + 32);
    }
    // --- V fragment loads issued early: latency hidden under softmax VALU work ---
    short8 vf[4][2];
#pragma unroll
    for (int n = 0; n < 4; ++n) {
      const unsigned short* vp = Vbase + (size_t)(n * 16 + lr) * S_LEN + kb + g * 8;
      vf[n][0] = *reinterpret_cast<const short8*>(vp);
      vf[n][1] = *reinterpret_cast<const short8*>(vp + 32);
    }
    f32x4 accS[4];
#pragma unroll
    for (int n = 0; n < 4; ++n) {
      f32x4 z = mfma16(aq0, kf[n][0], vzero);
      accS[n] = mfma16(aq1, kf[n][1], z);
    }
    const bool mixed = (kb + 64 == qbase) || (kb == qbase) || (kb == qbase + 64);
    float newm[4];
#pragma unroll
    for (int r = 0; r < 4; ++r) newm[r] = mrun[r];
    if (!mixed) {
      const int jc = (kb < qbase) ? 0 : 4;
#pragma unroll
      for (int n = 0; n < 4; ++n)
#pragma unroll
        for (int r = 0; r < 4; ++r) {
          accS[n][r] += (jc == 0) ? pj[r][0] : pj[r][4];
          newm[r] = fmaxf(newm[r], accS[n][r]);
        }
    } else {
#pragma unroll
      for (int n = 0; n < 4; ++n) {
        const int kg = kb + n * 16 + lr;
#pragma unroll
        for (int r = 0; r < 4; ++r) {
          const int dist = kg - (qbase + wid * 16 + g * 4 + r);
          const int jj = dist < -2 ? 0 : (dist > 2 ? 4 : dist + 2);
          const float add = jj == 0 ? pj[r][0] : jj == 1 ? pj[r][1] : jj == 2 ? pj[r][2]
                           : jj == 3 ? pj[r][3] : pj[r][4];
          accS[n][r] += add;
          newm[r] = fmaxf(newm[r], accS[n][r]);
        }
      }
    }
    // row max across the 16-lane column group, then rescale running state
#pragma unroll
    for (int r = 0; r < 4; ++r) {
      float v = newm[r];
      v = fmaxf(v, __shfl_xor(v, 1));
      v = fmaxf(v, __shfl_xor(v, 2));
      v = fmaxf(v, __shfl_xor(v, 4));
      v = fmaxf(v, __shfl_xor(v, 8));
      const float fsc = __expf(mrun[r] - v);  // 0 on first tile (-inf)
      mrun[r] = v;
#pragma unroll
      for (int j = 0; j < 5; ++j) sp[r][j] *= fsc;
#pragma unroll
      for (int n = 0; n < 4; ++n) accO[n][r] *= fsc;
    }
    // P = exp(S - m); accumulate 5-bucket per-lane partials; stage P for transpose
#pragma unroll
    for (int n = 0; n < 4; ++n) {
      const int kg = kb + n * 16 + lr;
#pragma unroll
      for (int r = 0; r < 4; ++r) {
        const float p = __expf(accS[n][r] - mrun[r]);
        if (!mixed) {
          if (kb < qbase) sp[r][0] += p; else sp[r][4] += p;
        } else {
          const int dist = kg - (qbase + wid * 16 + g * 4 + r);
          const int jj = dist < -2 ? 0 : (dist > 2 ? 4 : dist + 2);
          sp[r][0] += (jj == 0) ? p : 0.f;
          sp[r][1] += (jj == 1) ? p : 0.f;
          sp[r][2] += (jj == 2) ? p : 0.f;
          sp[r][3] += (jj == 3) ? p : 0.f;
          sp[r][4] += (jj == 4) ? p : 0.f;
        }
        Ps[wid][g * 4 + r][n * 16 + lr] = f2bf(p);
      }
    }
    // Compiler fence: forbid hoisting the short8 Ps loads above the scalar
    // ushort Ps stores (TBAA). Same-wave DS ops complete in order in HW.
    asm volatile("" ::: "memory");
    // O += P V  (P via per-wave LDS transpose; V rows contiguous thanks to Vt layout)
    short8 pa0 = *reinterpret_cast<const short8*>(&Ps[wid][lr][g * 8]);
    short8 pa1 = *reinterpret_cast<const short8*>(&Ps[wid][lr][g * 8 + 32]);
#pragma unroll
    for (int n = 0; n < 4; ++n) {
      accO[n] = mfma16(pa0, vf[n][0], accO[n]);
      accO[n] = mfma16(pa1, vf[n][1], accO[n]);
    }
  }

  // reduce bucket partials across the 16-lane group
#pragma unroll
  for (int r = 0; r < 4; ++r)
#pragma unroll
    for (int j = 0; j < 5; ++j) {
      float v = sp[r][j];
      v += __shfl_xor(v, 1);
      v += __shfl_xor(v, 2);
      v += __shfl_xor(v, 4);
      v += __shfl_xor(v, 8);
      sp[r][j] = v;
    }
  float rl[4];
#pragma unroll
  for (int r = 0; r < 4; ++r)
    rl[r] = 1.f / (sp[r][0] + sp[r][1] + sp[r][2] + sp[r][3] + sp[r][4]);
  // out = (O + sum_j s~_j * rel_v[j]) / l
#pragma unroll
  for (int n = 0; n < 4; ++n) {
    const int d = n * 16 + lr;
    const float rv0 = rvs[0][d], rv1 = rvs[1][d], rv2 = rvs[2][d], rv3 = rvs[3][d],
                rv4 = rvs[4][d];
#pragma unroll
    for (int r = 0; r < 4; ++r) {
      const float val = (accO[n][r] + sp[r][0] * rv0 + sp[r][1] * rv1 + sp[r][2] * rv2 +
                         sp[r][3] * rv3 + sp[r][4] * rv4) * rl[r];
      Xa[(size_t)(b * S_LEN + qbase + wid * 16 + g * 4 + r) * HID_DIM + h * HD + d] = f2bf(val);
    }
  }
}

extern "C" void kernel_launch(void* const* d_in, const int* in_sizes, int n_in,
                              void* d_out, int out_size, void* d_ws, size_t ws_size,
                              hipStream_t stream) {
  (void)in_sizes; (void)n_in; (void)out_size; (void)ws_size;
  const float* f_key   = (const float*)d_in[0];
  const float* f_query = (const float*)d_in[1];
  const float* f_value = (const float*)d_in[2];
  const float* Wq = (const float*)d_in[3];
  const float* bq = (const float*)d_in[4];
  const float* Wk = (const float*)d_in[5];
  const float* bk = (const float*)d_in[6];
  const float* Wv = (const float*)d_in[7];
  const float* bv = (const float*)d_in[8];
  const float* Wo = (const float*)d_in[9];
  const float* bo = (const float*)d_in[10];
  const float* relk = (const float*)d_in[11];
  const float* relv = (const float*)d_in[12];

  char* ws = (char*)d_ws;
  const size_t SZ = (size_t)MTOT * HID_DIM * sizeof(unsigned short);  // 8 MiB
  unsigned short* cq  = (unsigned short*)(ws + 0 * SZ);
  unsigned short* ck  = (unsigned short*)(ws + 1 * SZ);
  unsigned short* cv  = (unsigned short*)(ws + 2 * SZ);
  unsigned short* wqb = (unsigned short*)(ws + 3 * SZ);
  unsigned short* wkb = wqb + 1024 * 1024;
  unsigned short* wvb = wkb + 1024 * 1024;
  unsigned short* wob = wvb + 1024 * 1024;
  unsigned short* Qp  = (unsigned short*)(ws + 4 * SZ);
  unsigned short* Kp  = (unsigned short*)(ws + 5 * SZ);
  unsigned short* Vt  = (unsigned short*)(ws + 6 * SZ);
  unsigned short* xa  = cq;  // cq dead after qkv_gemm

  const int nIn4 = MTOT * HID_DIM / 4;
  const int nW4 = 1024 * 1024 / 4;
  cvt3<<<dim3(nIn4 / 256, 3), 256, 0, stream>>>(f_query, f_key, f_value, cq, ck, cv, nIn4);
  cvt4<<<dim3(nW4 / 256, 4), 256, 0, stream>>>(Wq, Wk, Wv, Wo, wqb, wkb, wvb, wob, nW4);
  qkv_gemm<<<dim3(24, 32), dim3(256), 0, stream>>>(cq, ck, cv, wqb, wkb, wvb, bq, bk, bv,
                                                   Qp, Kp, Vt);
  attn_kernel<<<dim3(32, 32), dim3(256), 0, stream>>>(Qp, Kp, Vt, relk, relv, xa);
  out_gemm<<<dim3(8, 32), dim3(256), 0, stream>>>(xa, wob, bo, (float*)d_out);
}

// Round 6
// 221.540 us; speedup vs baseline: 1.8100x; 1.5518x over previous
//
#include <hip/hip_runtime.h>
#include <hip/hip_bf16.h>

#define S_LEN 2048
#define HID_DIM 1024
#define NH 16
#define HD 64
#define MTOT 4096  // B*S
#define C_SCALE 0.125f  // 1/sqrt(HD)

typedef __attribute__((ext_vector_type(8))) short short8;
typedef __attribute__((ext_vector_type(4))) float f32x4;

__device__ __forceinline__ float bf2f(unsigned short u) {
  union { unsigned int i; float f; } x; x.i = ((unsigned int)u) << 16; return x.f;
}
__device__ __forceinline__ unsigned short f2bf(float f) {
  union { float ff; unsigned int i; } x; x.ff = f;
  return (unsigned short)((x.i + 0x7fffu + ((x.i >> 16) & 1u)) >> 16);
}
__device__ __forceinline__ unsigned short f2bf_rna(float f) {  // p >= 0 only
  union { float ff; unsigned int i; } x; x.ff = f;
  return (unsigned short)((x.i + 0x8000u) >> 16);
}
__device__ __forceinline__ f32x4 mfma16(short8 a, short8 b, f32x4 c) {
  return __builtin_amdgcn_mfma_f32_16x16x32_bf16(a, b, c, 0, 0, 0);
}
__device__ __forceinline__ void gl_lds16(const unsigned short* g, unsigned short* l) {
  __builtin_amdgcn_global_load_lds(
      (const __attribute__((address_space(1))) unsigned int*)g,
      (__attribute__((address_space(3))) unsigned int*)l, 16, 0, 0);
}

// ---------------- f32 -> bf16 converts (fused) ----------------
__global__ __launch_bounds__(256) void cvt3(const float* __restrict__ a, const float* __restrict__ b,
                                            const float* __restrict__ c, unsigned short* __restrict__ oa,
                                            unsigned short* __restrict__ ob, unsigned short* __restrict__ oc,
                                            int n4) {
  int i = blockIdx.x * 256 + threadIdx.x;
  if (i >= n4) return;
  const float* src = blockIdx.y == 0 ? a : blockIdx.y == 1 ? b : c;
  unsigned short* dst = blockIdx.y == 0 ? oa : blockIdx.y == 1 ? ob : oc;
  float4 v = reinterpret_cast<const float4*>(src)[i];
  union { unsigned short u[4]; unsigned long long ll; } o;
  o.u[0] = f2bf(v.x); o.u[1] = f2bf(v.y); o.u[2] = f2bf(v.z); o.u[3] = f2bf(v.w);
  reinterpret_cast<unsigned long long*>(dst)[i] = o.ll;
}
__global__ __launch_bounds__(256) void cvt4(const float* __restrict__ a, const float* __restrict__ b,
                                            const float* __restrict__ c, const float* __restrict__ d,
                                            unsigned short* __restrict__ oa, unsigned short* __restrict__ ob,
                                            unsigned short* __restrict__ oc, unsigned short* __restrict__ od,
                                            int n4) {
  int i = blockIdx.x * 256 + threadIdx.x;
  if (i >= n4) return;
  const float* src = blockIdx.y == 0 ? a : blockIdx.y == 1 ? b : blockIdx.y == 2 ? c : d;
  unsigned short* dst = blockIdx.y == 0 ? oa : blockIdx.y == 1 ? ob : blockIdx.y == 2 ? oc : od;
  float4 v = reinterpret_cast<const float4*>(src)[i];
  union { unsigned short u[4]; unsigned long long ll; } o;
  o.u[0] = f2bf(v.x); o.u[1] = f2bf(v.y); o.u[2] = f2bf(v.z); o.u[3] = f2bf(v.w);
  reinterpret_cast<unsigned long long*>(dst)[i] = o.ll;
}

// ---------------- GEMM core: C[128x128] += A[128xK] * W[128xK]^T (bf16, B^T layout) ----------------
__device__ __forceinline__ void gemm_core(const unsigned short* __restrict__ A,
                                          const unsigned short* __restrict__ W,
                                          unsigned short* As, unsigned short* Bs,
                                          int m0, int n0, f32x4 (&acc)[4][4]) {
  const int tid = threadIdx.x;
  const int lane = tid & 63;
  const int wrow = (tid >> 6) >> 1, wcol = (tid >> 6) & 1;
  const int lr = lane & 15, g = lane >> 4;
  const int r = tid >> 2, c8 = (tid & 3) * 8;
  const unsigned short* ag0 = A + (size_t)(m0 + r) * HID_DIM + c8;
  const unsigned short* ag1 = ag0 + (size_t)64 * HID_DIM;
  const unsigned short* bg0 = W + (size_t)(n0 + r) * HID_DIM + c8;
  const unsigned short* bg1 = bg0 + (size_t)64 * HID_DIM;
  unsigned short* al0 = As + r * 32 + c8;
  unsigned short* al1 = al0 + 64 * 32;
  unsigned short* bl0 = Bs + r * 32 + c8;
  unsigned short* bl1 = bl0 + 64 * 32;
  for (int k0 = 0; k0 < HID_DIM; k0 += 32) {
    __syncthreads();
    gl_lds16(ag0 + k0, al0);
    gl_lds16(ag1 + k0, al1);
    gl_lds16(bg0 + k0, bl0);
    gl_lds16(bg1 + k0, bl1);
    __syncthreads();
    short8 af[4], bfr[4];
#pragma unroll
    for (int m = 0; m < 4; ++m)
      af[m] = *reinterpret_cast<const short8*>(&As[(wrow * 64 + m * 16 + lr) * 32 + g * 8]);
#pragma unroll
    for (int n = 0; n < 4; ++n)
      bfr[n] = *reinterpret_cast<const short8*>(&Bs[(wcol * 64 + n * 16 + lr) * 32 + g * 8]);
#pragma unroll
    for (int m = 0; m < 4; ++m)
#pragma unroll
      for (int n = 0; n < 4; ++n)
        acc[m][n] = mfma16(af[m], bfr[n], acc[m][n]);
  }
}

// ---------------- fused QKV projection GEMM ----------------
__global__ __launch_bounds__(256) void qkv_gemm(
    const unsigned short* __restrict__ Aq, const unsigned short* __restrict__ Ak,
    const unsigned short* __restrict__ Av,
    const unsigned short* __restrict__ Wq, const unsigned short* __restrict__ Wk,
    const unsigned short* __restrict__ Wv,
    const float* __restrict__ bq, const float* __restrict__ bk, const float* __restrict__ bv,
    unsigned short* __restrict__ Qp, unsigned short* __restrict__ Kp,
    unsigned short* __restrict__ Vt) {
  __shared__ __attribute__((aligned(16))) unsigned short As[128 * 32];
  __shared__ __attribute__((aligned(16))) unsigned short Bs[128 * 32];
  const int which = blockIdx.x >> 3;
  const int n0 = (blockIdx.x & 7) * 128;
  const int m0 = blockIdx.y * 128;
  const unsigned short* A = which == 0 ? Aq : which == 1 ? Ak : Av;
  const unsigned short* W = which == 0 ? Wq : which == 1 ? Wk : Wv;
  const float* bias = which == 0 ? bq : which == 1 ? bk : bv;

  f32x4 acc[4][4];
  const f32x4 vzero = {0.f, 0.f, 0.f, 0.f};
#pragma unroll
  for (int m = 0; m < 4; ++m)
#pragma unroll
    for (int n = 0; n < 4; ++n) acc[m][n] = vzero;

  gemm_core(A, W, As, Bs, m0, n0, acc);

  const int lane = threadIdx.x & 63;
  const int wrow = (threadIdx.x >> 6) >> 1, wcol = (threadIdx.x >> 6) & 1;
  const int lr = lane & 15, g = lane >> 4;
#pragma unroll
  for (int m = 0; m < 4; ++m) {
    const int rbase = m0 + wrow * 64 + m * 16 + g * 4;
#pragma unroll
    for (int n = 0; n < 4; ++n) {
      const int col = n0 + wcol * 64 + n * 16 + lr;
      const float bcol = bias[col];
      if (which < 2) {
        unsigned short* O = which == 0 ? Qp : Kp;
#pragma unroll
        for (int rg = 0; rg < 4; ++rg)
          O[(size_t)(rbase + rg) * HID_DIM + col] = f2bf(acc[m][n][rg] + bcol);
      } else {
        const int bb = rbase >> 11, s = rbase & 2047;
        const int h = col >> 6, d = col & 63;
        union { unsigned short u[4]; unsigned long long ll; } o;
#pragma unroll
        for (int rg = 0; rg < 4; ++rg) o.u[rg] = f2bf(acc[m][n][rg] + bcol);
        *reinterpret_cast<unsigned long long*>(
            &Vt[((size_t)(bb * NH + h) * HD + d) * S_LEN + s]) = o.ll;
      }
    }
  }
}

// ---------------- output GEMM ----------------
__global__ __launch_bounds__(256) void out_gemm(const unsigned short* __restrict__ X,
                                                const unsigned short* __restrict__ Wo,
                                                const float* __restrict__ bo,
                                                float* __restrict__ out) {
  __shared__ __attribute__((aligned(16))) unsigned short As[128 * 32];
  __shared__ __attribute__((aligned(16))) unsigned short Bs[128 * 32];
  const int n0 = blockIdx.x * 128;
  const int m0 = blockIdx.y * 128;
  f32x4 acc[4][4];
  const f32x4 vzero = {0.f, 0.f, 0.f, 0.f};
#pragma unroll
  for (int m = 0; m < 4; ++m)
#pragma unroll
    for (int n = 0; n < 4; ++n) acc[m][n] = vzero;

  gemm_core(X, Wo, As, Bs, m0, n0, acc);

  const int lane = threadIdx.x & 63;
  const int wrow = (threadIdx.x >> 6) >> 1, wcol = (threadIdx.x >> 6) & 1;
  const int lr = lane & 15, g = lane >> 4;
#pragma unroll
  for (int m = 0; m < 4; ++m) {
    const int rbase = m0 + wrow * 64 + m * 16 + g * 4;
#pragma unroll
    for (int n = 0; n < 4; ++n) {
      const int col = n0 + wcol * 64 + n * 16 + lr;
      const float bcol = bo[col];
#pragma unroll
      for (int rg = 0; rg < 4; ++rg)
        out[(size_t)(rbase + rg) * HID_DIM + col] = acc[m][n][rg] + bcol;
    }
  }
}

// ---------------- flash attention: LDS-staged K/V (dbuf, XOR-swizzled), 32 q-rows/wave ----------------
__global__ __launch_bounds__(256, 2) void attn_kernel(
    const unsigned short* __restrict__ Qp, const unsigned short* __restrict__ Kp,
    const unsigned short* __restrict__ Vt, const float* __restrict__ relk,
    const float* __restrict__ relv, unsigned short* __restrict__ Xa) {
  __shared__ __attribute__((aligned(16))) unsigned short kv[2][8192];  // [buf][K 4096sh | V 4096sh]
  __shared__ __attribute__((aligned(16))) unsigned short Ps[4][32][72];
  __shared__ float projs[128][5];
  __shared__ float relks[5][64];
  __shared__ float rvs[5][64];

  const int tid = threadIdx.x;
  const int lane = tid & 63;
  const int w = tid >> 6;
  const int lr = lane & 15, g = lane >> 4;
  const int qbase = blockIdx.x * 128;
  const int bh = blockIdx.y;
  const int b = bh >> 4, h = bh & 15;
  const float NINF = -__builtin_inff();

  const unsigned short* Qg = Qp + ((size_t)(b * S_LEN + qbase)) * HID_DIM + h * HD;
  const unsigned short* Kg = Kp + ((size_t)b * S_LEN) * HID_DIM + h * HD;
  const unsigned short* Vg = Vt + (size_t)bh * HD * S_LEN;

  // ---- prologue: Q -> kv[1] (128 rows), K0/V0 -> kv[0]; swizzled-source gl_lds ----
#pragma unroll
  for (int i = 0; i < 4; ++i) {
    const int flat = i * 4096 + tid * 16;  // LDS byte
    const int row = flat >> 7, c = (flat >> 4) & 7;
    gl_lds16(Qg + (size_t)row * HID_DIM + ((c ^ (row & 7)) * 8), &kv[1][flat >> 1]);
  }
#pragma unroll
  for (int i = 0; i < 2; ++i) {
    const int flat = i * 4096 + tid * 16;
    const int row = flat >> 7, c = (flat >> 4) & 7;
    const int csrc = (c ^ (row & 7)) * 8;
    gl_lds16(Kg + (size_t)row * HID_DIM + csrc, &kv[0][flat >> 1]);
    gl_lds16(Vg + (size_t)row * S_LEN + csrc, &kv[0][4096 + (flat >> 1)]);
  }
  // FIX (root cause of rounds 2-4): these tables have 320 elements but only 256
  // threads; `if (tid < 320)` left elements 256..319 (all of bucket j=4!)
  // uninitialized. Must be a strided loop.
  for (int i = tid; i < 320; i += 256) {
    ((float*)relks)[i] = relk[i];
    ((float*)rvs)[i] = relv[i];
  }
  __syncthreads();  // Q, K0, V0 staged (barrier drains vmcnt)

  // proj[row][j] = q_row . rel_k[j]  (raw, unscaled)
  for (int idx = tid; idx < 640; idx += 256) {
    const int row = idx & 127, j = idx >> 7;
    float acc = 0.f;
    for (int d = 0; d < 64; ++d)
      acc += bf2f(kv[1][row * 64 + ((d >> 3) ^ (row & 7)) * 8 + (d & 7)]) * relks[j][d];
    projs[row][j] = acc;
  }
  // A-fragments of Q (raw): row = w*32 + mg*16 + lr
  short8 aq[2][2];
#pragma unroll
  for (int mg = 0; mg < 2; ++mg)
#pragma unroll
    for (int h2 = 0; h2 < 2; ++h2) {
      const int row = w * 32 + mg * 16 + lr;
      aq[mg][h2] = *reinterpret_cast<const short8*>(
          &kv[1][row * 64 + (((g + 4 * h2) ^ (lr & 7)) * 8)]);
    }
  __syncthreads();  // projs visible; Q reads done (kv[1] overwritten at t=0)

  float pj0[8], pj4[8];
#pragma unroll
  for (int i = 0; i < 8; ++i) {
    const int qloc = w * 32 + (i >> 2) * 16 + g * 4 + (i & 3);
    pj0[i] = projs[qloc][0];
    pj4[i] = projs[qloc][4];
  }

  const f32x4 vzero = {0.f, 0.f, 0.f, 0.f};
  f32x4 accO[2][4];
#pragma unroll
  for (int mg = 0; mg < 2; ++mg)
#pragma unroll
    for (int n = 0; n < 4; ++n) accO[mg][n] = vzero;
  float sp0[8], sp4[8], s1[8], s2[8], s3[8], mrun[8], negm[8];
#pragma unroll
  for (int i = 0; i < 8; ++i) {
    sp0[i] = 0.f; sp4[i] = 0.f;
    s1[i] = NINF; s2[i] = NINF; s3[i] = NINF;
    mrun[i] = NINF; negm[i] = 0.f;
  }

  for (int t = 0; t < 32; ++t) {
    const int kb = t * 64;
    const unsigned short* Ks = kv[t & 1];
    const unsigned short* Vs = Ks + 4096;
    if (t < 31) {  // prefetch next tile into other buffer
      const int kb2 = kb + 64;
      unsigned short* dst = &kv[(t + 1) & 1][0];
#pragma unroll
      for (int i = 0; i < 2; ++i) {
        const int flat = i * 4096 + tid * 16;
        const int row = flat >> 7, c = (flat >> 4) & 7;
        const int csrc = (c ^ (row & 7)) * 8;
        gl_lds16(Kg + (size_t)(kb2 + row) * HID_DIM + csrc, dst + (flat >> 1));
        gl_lds16(Vg + (size_t)row * S_LEN + kb2 + csrc, dst + 4096 + (flat >> 1));
      }
    }
    // K fragments + QK^T
    short8 kf[4][2];
#pragma unroll
    for (int n = 0; n < 4; ++n)
#pragma unroll
      for (int h2 = 0; h2 < 2; ++h2)
        kf[n][h2] = *reinterpret_cast<const short8*>(
            &Ks[(n * 16 + lr) * 64 + (((g + 4 * h2) ^ (lr & 7)) * 8)]);
    f32x4 accS[2][4];
#pragma unroll
    for (int mg = 0; mg < 2; ++mg)
#pragma unroll
      for (int n = 0; n < 4; ++n) {
        f32x4 z = mfma16(aq[mg][0], kf[n][0], vzero);
        accS[mg][n] = mfma16(aq[mg][1], kf[n][1], z);
      }

    const bool mixed = (kb >= qbase - 64) && (kb <= qbase + 128);
    float rowmax[8];
#pragma unroll
    for (int i = 0; i < 8; ++i) rowmax[i] = NINF;

    if (!mixed) {
      const bool left = kb < qbase;
#pragma unroll
      for (int mg = 0; mg < 2; ++mg)
#pragma unroll
        for (int n = 0; n < 4; ++n)
#pragma unroll
          for (int r = 0; r < 4; ++r) {
            const int i = mg * 4 + r;
            accS[mg][n][r] += left ? pj0[i] : pj4[i];
            rowmax[i] = fmaxf(rowmax[i], accS[mg][n][r]);
          }
      bool need = false;
#pragma unroll
      for (int i = 0; i < 8; ++i) need |= rowmax[i] > mrun[i] + 8.0f;
      if (__any(need)) {
#pragma unroll
        for (int i = 0; i < 8; ++i) {
          float v = rowmax[i];
          v = fmaxf(v, __shfl_xor(v, 1));
          v = fmaxf(v, __shfl_xor(v, 2));
          v = fmaxf(v, __shfl_xor(v, 4));
          v = fmaxf(v, __shfl_xor(v, 8));
          v = fmaxf(v, mrun[i]);
          const float fsc = __expf((mrun[i] - v) * C_SCALE);
          mrun[i] = v; negm[i] = -v * C_SCALE;
          sp0[i] *= fsc; sp4[i] *= fsc;
#pragma unroll
          for (int n = 0; n < 4; ++n) accO[i >> 2][n][i & 3] *= fsc;
        }
      }
#pragma unroll
      for (int mg = 0; mg < 2; ++mg)
#pragma unroll
        for (int n = 0; n < 4; ++n)
#pragma unroll
          for (int r = 0; r < 4; ++r) {
            const int i = mg * 4 + r;
            const float p = __expf(fmaf(accS[mg][n][r], C_SCALE, negm[i]));
            if (left) sp0[i] += p; else sp4[i] += p;
            Ps[w][mg * 16 + g * 4 + r][n * 16 + lr] = f2bf_rna(p);
          }
    } else {
#pragma unroll
      for (int mg = 0; mg < 2; ++mg)
#pragma unroll
        for (int n = 0; n < 4; ++n) {
          const int kg = kb + n * 16 + lr;
#pragma unroll
          for (int r = 0; r < 4; ++r) {
            const int i = mg * 4 + r;
            const int qloc = w * 32 + mg * 16 + g * 4 + r;
            const int dist = kg - (qbase + qloc);
            float pjv;
            if (dist <= -2) pjv = pj0[i];
            else if (dist >= 2) pjv = pj4[i];
            else pjv = projs[qloc][dist + 2];
            accS[mg][n][r] += pjv;
            rowmax[i] = fmaxf(rowmax[i], accS[mg][n][r]);
          }
        }
#pragma unroll
      for (int i = 0; i < 8; ++i) {
        float v = rowmax[i];
        v = fmaxf(v, __shfl_xor(v, 1));
        v = fmaxf(v, __shfl_xor(v, 2));
        v = fmaxf(v, __shfl_xor(v, 4));
        v = fmaxf(v, __shfl_xor(v, 8));
        v = fmaxf(v, mrun[i]);
        const float fsc = __expf((mrun[i] - v) * C_SCALE);
        mrun[i] = v; negm[i] = -v * C_SCALE;
        sp0[i] *= fsc; sp4[i] *= fsc;
#pragma unroll
        for (int n = 0; n < 4; ++n) accO[i >> 2][n][i & 3] *= fsc;
      }
#pragma unroll
      for (int mg = 0; mg < 2; ++mg)
#pragma unroll
        for (int n = 0; n < 4; ++n) {
          const int kg = kb + n * 16 + lr;
#pragma unroll
          for (int r = 0; r < 4; ++r) {
            const int i = mg * 4 + r;
            const int qloc = w * 32 + mg * 16 + g * 4 + r;
            const int dist = kg - (qbase + qloc);
            const float val = accS[mg][n][r];
            const float p = __expf(fmaf(val, C_SCALE, negm[i]));
            Ps[w][mg * 16 + g * 4 + r][n * 16 + lr] = f2bf_rna(p);
            if (dist <= -2) sp0[i] += p;
            else if (dist >= 2) sp4[i] += p;
            else if (dist == -1) s1[i] = val;   // singleton raw logits, exp'd at the end
            else if (dist == 0) s2[i] = val;
            else s3[i] = val;
          }
        }
    }
    // Compiler fence: forbid hoisting the short8 Ps loads above the scalar
    // ushort Ps stores (TBAA). Same-wave DS ops complete in order in HW.
    asm volatile("" ::: "memory");
    // V fragments, P fragments, PV
    short8 vf[4][2];
#pragma unroll
    for (int n = 0; n < 4; ++n)
#pragma unroll
      for (int h2 = 0; h2 < 2; ++h2)
        vf[n][h2] = *reinterpret_cast<const short8*>(
            &Vs[(n * 16 + lr) * 64 + (((g + 4 * h2) ^ (lr & 7)) * 8)]);
    short8 pa[2][2];
#pragma unroll
    for (int mg = 0; mg < 2; ++mg)
#pragma unroll
      for (int h2 = 0; h2 < 2; ++h2)
        pa[mg][h2] = *reinterpret_cast<const short8*>(&Ps[w][mg * 16 + lr][(g + 4 * h2) * 8]);
#pragma unroll
    for (int mg = 0; mg < 2; ++mg)
#pragma unroll
      for (int n = 0; n < 4; ++n) {
        accO[mg][n] = mfma16(pa[mg][0], vf[n][0], accO[mg][n]);
        accO[mg][n] = mfma16(pa[mg][1], vf[n][1], accO[mg][n]);
      }
    __syncthreads();  // all waves done with this buffer; next-tile staging drained
  }

  // ---- epilogue: reduce bucket sums over the 16-lane group, write output ----
#pragma unroll
  for (int i = 0; i < 8; ++i) {
    float v0 = sp0[i];
    float v1 = __expf(fmaf(s1[i], C_SCALE, negm[i]));
    float v2 = __expf(fmaf(s2[i], C_SCALE, negm[i]));
    float v3 = __expf(fmaf(s3[i], C_SCALE, negm[i]));
    float v4 = sp4[i];
#pragma unroll
    for (int s = 1; s <= 8; s <<= 1) {
      v0 += __shfl_xor(v0, s); v1 += __shfl_xor(v1, s); v2 += __shfl_xor(v2, s);
      v3 += __shfl_xor(v3, s); v4 += __shfl_xor(v4, s);
    }
    const float rl = 1.f / (v0 + v1 + v2 + v3 + v4);
    const int qrow = b * S_LEN + qbase + w * 32 + (i >> 2) * 16 + g * 4 + (i & 3);
#pragma unroll
    for (int n = 0; n < 4; ++n) {
      const int d = n * 16 + lr;
      const float val = (accO[i >> 2][n][i & 3] + v0 * rvs[0][d] + v1 * rvs[1][d] +
                         v2 * rvs[2][d] + v3 * rvs[3][d] + v4 * rvs[4][d]) * rl;
      Xa[(size_t)qrow * HID_DIM + h * HD + d] = f2bf(val);
    }
  }
}

extern "C" void kernel_launch(void* const* d_in, const int* in_sizes, int n_in,
                              void* d_out, int out_size, void* d_ws, size_t ws_size,
                              hipStream_t stream) {
  (void)in_sizes; (void)n_in; (void)out_size; (void)ws_size;
  const float* f_key   = (const float*)d_in[0];
  const float* f_query = (const float*)d_in[1];
  const float* f_value = (const float*)d_in[2];
  const float* Wq = (const float*)d_in[3];
  const float* bq = (const float*)d_in[4];
  const float* Wk = (const float*)d_in[5];
  const float* bk = (const float*)d_in[6];
  const float* Wv = (const float*)d_in[7];
  const float* bv = (const float*)d_in[8];
  const float* Wo = (const float*)d_in[9];
  const float* bo = (const float*)d_in[10];
  const float* relk = (const float*)d_in[11];
  const float* relv = (const float*)d_in[12];

  char* ws = (char*)d_ws;
  const size_t SZ = (size_t)MTOT * HID_DIM * sizeof(unsigned short);  // 8 MiB
  unsigned short* cq  = (unsigned short*)(ws + 0 * SZ);
  unsigned short* ck  = (unsigned short*)(ws + 1 * SZ);
  unsigned short* cv  = (unsigned short*)(ws + 2 * SZ);
  unsigned short* wqb = (unsigned short*)(ws + 3 * SZ);
  unsigned short* wkb = wqb + 1024 * 1024;
  unsigned short* wvb = wkb + 1024 * 1024;
  unsigned short* wob = wvb + 1024 * 1024;
  unsigned short* Qp  = (unsigned short*)(ws + 4 * SZ);
  unsigned short* Kp  = (unsigned short*)(ws + 5 * SZ);
  unsigned short* Vt  = (unsigned short*)(ws + 6 * SZ);
  unsigned short* xa  = cq;  // cq dead after qkv_gemm

  const int nIn4 = MTOT * HID_DIM / 4;
  const int nW4 = 1024 * 1024 / 4;
  cvt3<<<dim3(nIn4 / 256, 3), 256, 0, stream>>>(f_query, f_key, f_value, cq, ck, cv, nIn4);
  cvt4<<<dim3(nW4 / 256, 4), 256, 0, stream>>>(Wq, Wk, Wv, Wo, wqb, wkb, wvb, wob, nW4);
  qkv_gemm<<<dim3(24, 32), dim3(256), 0, stream>>>(cq, ck, cv, wqb, wkb, wvb, bq, bk, bv,
                                                   Qp, Kp, Vt);
  attn_kernel<<<dim3(16, 32), dim3(256), 0, stream>>>(Qp, Kp, Vt, relk, relv, xa);
  out_gemm<<<dim3(8, 32), dim3(256), 0, stream>>>(xa, wob, bo, (float*)d_out);
}